// Round 16
// baseline (96.377 us; speedup 1.0000x reference)
//
#include <hip/hip_runtime.h>
#include <hip/hip_bf16.h>
#include <stdint.h>
#include <math.h>

// STFT power spectrogram via radix-2 decimated INT8 MFMA GEMM with a
// persistent LDS sample-stream. X(f) = E(f') + e^{-i pi f/512} O(f'),
// S = |X|^2. E/O = 512-pt windowed DFTs of even/odd samples.
// R16 = R15 (mb-loop over all 4 mblks per resident stream, 512-block grid,
// BN=120) + R14's PROVEN 1088-chunk stream (R15 truncated to 1024 and
// frames 125-127 read past the stream -- the R12 bug class again).
// Frame fl needs chunks fl*8 .. fl*8+31 -> max 1047 -> 1088 with pad.
// SWZ/SLOTM/dataflow identical to R14 (proven).

#define NFFT     1024
#define NFREQ    513
#define BATCH    32
#define SAMPLES  480000
#define SAMPH    240000                // per-batch half-stream samples
#define HOPH     128                   // hop in half-stream
#define NFRAMES  1872
#define BN       120                   // frames owned per block (16*120=1920)
#define NBPB     16                    // blocks per batch
#define NTILES   64                    // 4 mblk x 16 kt, continuous stream
#define NWG      (BATCH * NBPB)        // 512 = 8 * 64

#define XH_BYTES  ((size_t)BATCH * SAMPLES)              // xe+xo total
#define AWS_BYTES ((size_t)NTILES * 128 * 64)            // 524,288
#define TW_BYTES  (513 * 8)

#define XMAX   6.5f
#define SCALE_X (127.0f / XMAX)
#define DEQ    (XMAX / 16129.0f)
#define DEQ2   (DEQ * DEQ)

#define QX_BLOCKS 1875
#define BA_BLOCKS 2048
#define PREP_BLOCKS (QX_BLOCKS + BA_BLOCKS + 1)

typedef __attribute__((ext_vector_type(4)))  int i32x4;
typedef __attribute__((ext_vector_type(16))) int i32x16;

#define SLOTM(r) ((((r) >> 1) & 3) ^ (((r) >> 3) & 1))
// Stream chunk swizzle (R14, involution: mask from bits>=3 only).
#define SWZ(q) ((q) ^ ((((q) >> 3) ^ ((q) >> 6)) & 7))

// ---------------- fused prep: quant+deinterleave | build_A | twiddle ------
__global__ __launch_bounds__(256) void k_prep(const float* __restrict__ x,
                                              const float* __restrict__ narr,
                                              const float* __restrict__ w,
                                              const float* __restrict__ window,
                                              signed char* __restrict__ xe,
                                              signed char* __restrict__ xo,
                                              signed char* __restrict__ Aws,
                                              float2* __restrict__ tw) {
  const int bid = blockIdx.x;
  const int tid = threadIdx.x;
  if (bid < QX_BLOCKS) {
    size_t i = (size_t)bid * 256 + tid;
    const float4* x4 = (const float4*)x;
    union { signed char c[16]; uint4 v; } pe, po;
    #pragma unroll
    for (int j = 0; j < 8; ++j) {
      float4 a = x4[i * 8 + j];
      float qe  = fminf(127.f, fmaxf(-127.f, a.x * SCALE_X));
      float qo  = fminf(127.f, fmaxf(-127.f, a.y * SCALE_X));
      float qe2 = fminf(127.f, fmaxf(-127.f, a.z * SCALE_X));
      float qo2 = fminf(127.f, fmaxf(-127.f, a.w * SCALE_X));
      pe.c[j * 2]     = (signed char)__float2int_rn(qe);
      po.c[j * 2]     = (signed char)__float2int_rn(qo);
      pe.c[j * 2 + 1] = (signed char)__float2int_rn(qe2);
      po.c[j * 2 + 1] = (signed char)__float2int_rn(qo2);
    }
    ((uint4*)xe)[i] = pe.v;
    ((uint4*)xo)[i] = po.v;
  } else if (bid < QX_BLOCKS + BA_BLOCKS) {
    // A i8 [tile=mblk*16+kt][r 0..127][slot 0..3][16]; kt<8 E, kt>=8 O.
    uint32_t E = (uint32_t)(bid - QX_BLOCKS) * 256 + tid;
    uint32_t e    = E & 15;
    uint32_t s    = (E >> 4) & 3;
    uint32_t r    = (E >> 6) & 127;
    uint32_t kt   = (E >> 13) & 15;
    uint32_t mblk = E >> 17;
    uint32_t er = mblk * 128 + r;
    uint32_t j  = (kt & 7) * 64 + ((s ^ SLOTM(r)) << 4) + e;   // 0..511
    uint32_t odd = (kt >> 3) & 1;
    uint32_t widx = (er == 1) ? 512u : (er & ~1u);
    float ang = w[widx] * narr[j];
    float sn, cs;
    sincosf(ang, &sn, &cs);
    float base = ((er & 1) && (er != 1)) ? -sn : cs;
    float val = 127.f * window[2 * j + odd] * base;
    Aws[E] = (signed char)__float2int_rn(val);
  } else {
    for (int j = tid; j <= 512; j += 256) {
      float st, ct;
      sincosf((float)j * (float)(M_PI / 512.0), &st, &ct);
      tw[j] = make_float2(ct, st);
    }
  }
}

// ---------------- main GEMM ----------------
#define GL2LDS(g, l) __builtin_amdgcn_global_load_lds( \
    (const __attribute__((address_space(1))) uint32_t*)(g), \
    (__attribute__((address_space(3))) uint32_t*)(l), 16, 0, 0)

#define WAITV4_BAR() asm volatile("s_waitcnt vmcnt(4)\ns_barrier" ::: "memory")
#define WAIT0_BAR()  asm volatile("s_waitcnt vmcnt(0)\ns_barrier" ::: "memory")
#define LGKM0_BAR()  asm volatile("s_waitcnt lgkmcnt(0)\ns_barrier" ::: "memory")

// LDS: xe stream @0 (17408 B = 1088 chunks: frame fl=127 reads chunk 1047),
// xo @17408, A ring @34816 (4 x 8192). Total 67584 -> 2 blocks/CU.
#define SE 0
#define SO 17408
#define AR 34816

// 256 threads x 4 chunks + tail chunks 1024..1087 by wave 0 FULL-WAVE
// (tid<64 uniform branch -- partial-exec global_load_lds corrupts, R12/R13).
#define STAGE_STREAM(src, bl) do {                                              \
  _Pragma("unroll") for (int p_ = 0; p_ < 4; ++p_) {                            \
    int q_ = p_ * 256 + tid;                                                    \
    GL2LDS((src) + (SWZ(q_) << 4), &lds[(bl) + q_ * 16]);                       \
  }                                                                             \
  if (tid < 64) {                                                               \
    int q_ = 1024 + tid;                                                        \
    GL2LDS((src) + (SWZ(q_) << 4), &lds[(bl) + q_ * 16]);                       \
  } } while (0)

// A tile = 8 KB = 512 chunks -> 2 loads/thread. t = global tile 0..63.
#define STAGE_A(t) do {                                                         \
  _Pragma("unroll") for (int j_ = 0; j_ < 2; ++j_) {                            \
    int ci_ = j_ * 256 + tid;                                                   \
    GL2LDS(Aws + ((size_t)(t) * 512 + ci_) * 16,                                \
           &lds[AR + ((t) & 3) * 8192 + ci_ * 16]);                             \
  } } while (0)

#define READ_A2(dst, t)                                                         \
  _Pragma("unroll") for (int mt_ = 0; mt_ < 2; ++mt_)                           \
  _Pragma("unroll") for (int ks_ = 0; ks_ < 2; ++ks_) {                         \
    int r_ = wr * 64 + mt_ * 32 + lr;                                           \
    int sl_ = (ks_ * 2 + hi) ^ SLOTM(r_);                                       \
    dst[mt_][ks_] = *(const i32x4*)&lds[AR + ((t) & 3) * 8192 + (r_ * 4 + sl_) * 16]; \
  }

#define READ_B2(dst, ktm7, SB)                                                  \
  _Pragma("unroll") for (int nt_ = 0; nt_ < 2; ++nt_)                           \
  _Pragma("unroll") for (int ks_ = 0; ks_ < 2; ++ks_) {                         \
    int cp_ = (wc * 64 + nt_ * 32 + lr) * 8 + (ktm7) * 4 + 2 * ks_ + hi;        \
    dst[nt_][ks_] = *(const i32x4*)&lds[(SB) + (SWZ(cp_) << 4)];                \
  }

#define MFMA8(ACC, A_, B_) do {                                                 \
  __builtin_amdgcn_s_setprio(1);                                                \
  _Pragma("unroll") for (int ks_ = 0; ks_ < 2; ++ks_)                           \
  _Pragma("unroll") for (int mt_ = 0; mt_ < 2; ++mt_)                           \
  _Pragma("unroll") for (int nt_ = 0; nt_ < 2; ++nt_)                           \
    ACC[mt_][nt_] = __builtin_amdgcn_mfma_i32_32x32x32_i8(                      \
        A_[mt_][ks_], B_[nt_][ks_], ACC[mt_][nt_], 0, 0, 0);                    \
  __builtin_amdgcn_s_setprio(0);                                                \
  } while (0)

// Ledger (4 A-load items per pair gi = t0>>1): prologue drains all.
// gi=0/1: vmcnt(4) trivially passes, reads prologue A0..3. Steady gi>=2:
// 8 out -> vmcnt(4) completes A(2gi),A(2gi+1); stage while gi<30; gi=31:
// vmcnt(0) drains A62,63. Epilogue stores are NEWEST in queue -> vmcnt(4)
// can leave only stores in flight, never an unread A load (in-order
// decrement). LGKM0_BAR = WAR fence before ring-slot overwrite.
#define ITER(tb, ii, ACC, SB) do {                                              \
    const int t0_ = (tb) + 2 * (ii), t1_ = t0_ + 1;                             \
    const int gi_ = t0_ >> 1;                                                   \
    if (gi_ == 31) WAIT0_BAR(); else WAITV4_BAR();                              \
    i32x4 a0[2][2], a1[2][2], b0[2][2], b1[2][2];                               \
    READ_A2(a0, t0_); READ_B2(b0, t0_ & 7, SB);                                 \
    READ_A2(a1, t1_); READ_B2(b1, t1_ & 7, SB);                                 \
    MFMA8(ACC, a0, b0);                                                         \
    MFMA8(ACC, a1, b1);                                                         \
    LGKM0_BAR();                                                                \
    if (gi_ < 30) { STAGE_A(t0_ + 4); STAGE_A(t1_ + 4); }                       \
  } while (0)

__global__ __launch_bounds__(256, 2) void k_stft(const signed char* __restrict__ xe,
                                                 const signed char* __restrict__ xo,
                                                 const signed char* __restrict__ Aws,
                                                 const float2* __restrict__ tw,
                                                 float* __restrict__ out) {
  __shared__ __align__(16) signed char lds[67584];
  const int tid  = threadIdx.x;
  const int lane = tid & 63;
  const int wid  = tid >> 6;
  const int wr = wid >> 1;      // 0..1 (64 A-rows each)
  const int wc = wid & 1;       // 0..1 (64 frames each)
  const int lr = lane & 31;
  const int hi = lane >> 5;

  // XCD-bijective swizzle: 512 = 8*64. Same-XCD blocks are consecutive nb
  // -> share xe/xo L2 panels; A (512 KB) shared by all.
  const int bx = blockIdx.x;
  const int nb = (bx & 7) * 64 + (bx >> 3);   // 0..511
  const int b  = nb >> 4;                     // batch 0..31
  const int f0 = (nb & 15) * BN;              // first frame, 0..1800

  // Stream window = f0*128 + [0,17408). Last block (f0=1800) overruns the
  // batch: garbage chunks >= 600 feed only frames fl >= 72 -> tfi >= 1872
  // -> guarded. Frames 120..127 duplicate next block's 0..7: integer-exact
  // identical writes, benign.
  const signed char* se_src = xe + (size_t)b * SAMPH + (size_t)f0 * HOPH;
  const signed char* so_src = xo + (size_t)b * SAMPH + (size_t)f0 * HOPH;

  i32x16 accE[2][2], accO[2][2];
  #pragma unroll
  for (int i = 0; i < 2; ++i)
    #pragma unroll
    for (int j = 0; j < 2; ++j)
      #pragma unroll
      for (int e = 0; e < 16; ++e) { accE[i][j][e] = 0; accO[i][j][e] = 0; }

  // prologue: both streams (once per block) + A(0..3); drain, publish.
  STAGE_STREAM(se_src, SE);
  STAGE_STREAM(so_src, SO);
  STAGE_A(0); STAGE_A(1); STAGE_A(2); STAGE_A(3);
  WAIT0_BAR();

  #pragma unroll 1
  for (int mb = 0; mb < 4; ++mb) {
    const int tb = mb * 16;
    ITER(tb, 0, accE, SE); ITER(tb, 1, accE, SE);
    ITER(tb, 2, accE, SE); ITER(tb, 3, accE, SE);
    ITER(tb, 4, accO, SO); ITER(tb, 5, accO, SO);
    ITER(tb, 6, accO, SO); ITER(tb, 7, accO, SO);

    // ---- epilogue mb: in-register radix-2 combine, twiddle from table ----
    // C/D: col = lane&31, row = (reg&3)+8*(reg>>2)+4*hi.
    // fq = mb*64 + wr*32 + mt*16 + aa*4 + 2*hi + q  (<= 255).
    const int fbase = mb * 64 + wr * 32;
    #pragma unroll
    for (int nt = 0; nt < 2; ++nt) {
      const int col = wc * 64 + nt * 32 + lr;
      const int tfi = f0 + col;
      if (tfi < NFRAMES) {
        float* op = out + (size_t)b * ((size_t)NFREQ * NFRAMES) + tfi;
        #pragma unroll
        for (int mt = 0; mt < 2; ++mt) {
          i32x16 vE = accE[mt][nt];
          i32x16 vO = accO[mt][nt];
          #pragma unroll
          for (int aa = 0; aa < 4; ++aa)
            #pragma unroll
            for (int q = 0; q < 2; ++q) {
              const int fq = fbase + mt * 16 + aa * 4 + 2 * hi + q;
              float Ere = (float)vE[aa * 4 + 2 * q];
              float Eim = (float)vE[aa * 4 + 2 * q + 1];
              float Ore = (float)vO[aa * 4 + 2 * q];
              float Oim = (float)vO[aa * 4 + 2 * q + 1];
              if (fq == 0) {
                float sp = Ere + Ore, sm = Ere - Ore;
                op[0]                     = DEQ2 * sp * sp;
                op[(size_t)512 * NFRAMES] = DEQ2 * sm * sm;
                op[(size_t)256 * NFRAMES] = DEQ2 * (Eim * Eim + Oim * Oim);
              } else {
                float2 t = tw[fq];
                float Pre = t.x * Ore + t.y * Oim;
                float Pim = t.x * Oim - t.y * Ore;
                float ar = Ere + Pre, ai = Eim + Pim;
                float br = Ere - Pre, bi = Eim - Pim;
                op[(size_t)fq * NFRAMES]         = DEQ2 * (ar * ar + ai * ai);
                op[(size_t)(512 - fq) * NFRAMES] = DEQ2 * (br * br + bi * bi);
              }
            }
        }
      }
    }
    // reset acc for next mb
    #pragma unroll
    for (int i = 0; i < 2; ++i)
      #pragma unroll
      for (int j = 0; j < 2; ++j)
        #pragma unroll
        for (int e = 0; e < 16; ++e) { accE[i][j][e] = 0; accO[i][j][e] = 0; }
  }
}

extern "C" void kernel_launch(void* const* d_in, const int* in_sizes, int n_in,
                              void* d_out, int out_size, void* d_ws, size_t ws_size,
                              hipStream_t stream) {
  const float* x      = (const float*)d_in[0];
  const float* narr   = (const float*)d_in[1];
  const float* w      = (const float*)d_in[2];
  const float* window = (const float*)d_in[3];
  float* out = (float*)d_out;

  signed char* xe  = (signed char*)d_ws;
  signed char* xo  = xe + (size_t)BATCH * SAMPH;
  signed char* Aws = xo + (size_t)BATCH * SAMPH;
  float2*      tw  = (float2*)(Aws + AWS_BYTES);
  if (ws_size < XH_BYTES + AWS_BYTES + TW_BYTES) return;  // ~15.9 MB

  k_prep<<<PREP_BLOCKS, 256, 0, stream>>>(x, narr, w, window, xe, xo, Aws, tw);
  k_stft<<<NWG, 256, 0, stream>>>(xe, xo, Aws, tw, out);
}

// Round 17
// 69.196 us; speedup vs baseline: 1.3928x; 1.3928x over previous
//
#include <hip/hip_runtime.h>
#include <hip/hip_bf16.h>
#include <stdint.h>
#include <math.h>

// STFT power spectrogram via radix-2 decimated INT8 MFMA GEMM.
// X(f) = E(f') + e^{-i pi f/512} O(f'), S = |X|^2; E/O = 512-pt windowed
// DFTs of even/odd samples. R17 vs R14: A is NOT LDS-staged -- prep writes
// A pre-arranged in per-wave fragment order (Afr[t][wr][mt][ks][lane*16B]),
// so each wave's A-fragment is ONE coalesced 1KB global load from L2
// (512KB total, broadcast across blocks). The K-loop has NO barriers, no
// vmcnt, no LDS writes -- waves free-run; only the prologue stream-publish
// barrier remains. LDS = the two R14-proven sample streams (1088 chunks,
// SWZ swizzle, full-wave tail).

#define NFFT     1024
#define NFREQ    513
#define BATCH    32
#define SAMPLES  480000
#define SAMPH    240000                // per-batch half-stream samples
#define HOPH     128                   // hop in half-stream
#define NFRAMES  1872
#define BN       128                   // frames per block
#define NBPB     15                    // 15*128 >= 1872
#define MBLKS    4
#define NWG      (BATCH * NBPB * MBLKS)   // 1920 = 8 * 240

#define XH_BYTES  ((size_t)BATCH * SAMPLES)              // xe+xo total
#define AFR_BYTES ((size_t)64 * 8192)                    // 524,288
#define TW_BYTES  (513 * 8)

#define XMAX   6.5f
#define SCALE_X (127.0f / XMAX)
#define DEQ    (XMAX / 16129.0f)
#define DEQ2   (DEQ * DEQ)

#define QX_BLOCKS 1875
#define BA_BLOCKS 2048
#define PREP_BLOCKS (QX_BLOCKS + BA_BLOCKS + 1)

typedef __attribute__((ext_vector_type(4)))  int i32x4;
typedef __attribute__((ext_vector_type(16))) int i32x16;

// Stream chunk swizzle (R14-proven, involution: mask from bits>=3 only).
#define SWZ(q) ((q) ^ ((((q) >> 3) ^ ((q) >> 6)) & 7))

// ---------------- fused prep: quant+deinterleave | build_Afr | twiddle ----
__global__ __launch_bounds__(256) void k_prep(const float* __restrict__ x,
                                              const float* __restrict__ narr,
                                              const float* __restrict__ w,
                                              const float* __restrict__ window,
                                              signed char* __restrict__ xe,
                                              signed char* __restrict__ xo,
                                              signed char* __restrict__ Afr,
                                              float2* __restrict__ tw) {
  const int bid = blockIdx.x;
  const int tid = threadIdx.x;
  if (bid < QX_BLOCKS) {
    size_t i = (size_t)bid * 256 + tid;
    const float4* x4 = (const float4*)x;
    union { signed char c[16]; uint4 v; } pe, po;
    #pragma unroll
    for (int j = 0; j < 8; ++j) {
      float4 a = x4[i * 8 + j];
      float qe  = fminf(127.f, fmaxf(-127.f, a.x * SCALE_X));
      float qo  = fminf(127.f, fmaxf(-127.f, a.y * SCALE_X));
      float qe2 = fminf(127.f, fmaxf(-127.f, a.z * SCALE_X));
      float qo2 = fminf(127.f, fmaxf(-127.f, a.w * SCALE_X));
      pe.c[j * 2]     = (signed char)__float2int_rn(qe);
      po.c[j * 2]     = (signed char)__float2int_rn(qo);
      pe.c[j * 2 + 1] = (signed char)__float2int_rn(qe2);
      po.c[j * 2 + 1] = (signed char)__float2int_rn(qo2);
    }
    ((uint4*)xe)[i] = pe.v;
    ((uint4*)xo)[i] = po.v;
  } else if (bid < QX_BLOCKS + BA_BLOCKS) {
    // Afr fragment layout: byte E = (((t*2+wr)*2+mt)*2+ks)*1024 + lane*16 + e
    // holds A[gr][j] with gr = (t>>4)*128 + wr*64 + mt*32 + (lane&31),
    // j = (t&7... see below). Rows: even gr -> cos f'=gr/2; odd -> -sin;
    // gr==1 repurposed as real f'=256 row. kt<8: E (win[2j]); kt>=8: O.
    uint32_t E = (uint32_t)(bid - QX_BLOCKS) * 256 + tid;
    uint32_t e    = E & 15;
    uint32_t lane = (E >> 4) & 63;
    uint32_t ks   = (E >> 10) & 1;
    uint32_t mt   = (E >> 11) & 1;
    uint32_t wr   = (E >> 12) & 1;
    uint32_t t    = E >> 13;           // 0..63 = mblk*16 + kt
    uint32_t kt   = t & 15;
    uint32_t mblk = t >> 4;
    uint32_t hi   = lane >> 5;
    uint32_t gr   = mblk * 128 + wr * 64 + mt * 32 + (lane & 31);  // 0..511
    uint32_t j    = (kt & 7) * 64 + (2 * ks + hi) * 16 + e;        // 0..511
    uint32_t odd  = (kt >> 3) & 1;
    uint32_t widx = (gr == 1) ? 512u : (gr & ~1u);
    float ang = w[widx] * narr[j];
    float sn, cs;
    sincosf(ang, &sn, &cs);
    float base = ((gr & 1) && (gr != 1)) ? -sn : cs;
    Afr[E] = (signed char)__float2int_rn(127.f * window[2 * j + odd] * base);
  } else {
    for (int j = tid; j <= 512; j += 256) {
      float st, ct;
      sincosf((float)j * (float)(M_PI / 512.0), &st, &ct);
      tw[j] = make_float2(ct, st);
    }
  }
}

// ---------------- main GEMM ----------------
#define GL2LDS(g, l) __builtin_amdgcn_global_load_lds( \
    (const __attribute__((address_space(1))) uint32_t*)(g), \
    (__attribute__((address_space(3))) uint32_t*)(l), 16, 0, 0)

#define WAIT0_BAR()  asm volatile("s_waitcnt vmcnt(0)\ns_barrier" ::: "memory")

// LDS: xe stream @0 (17408 B = 1088 chunks; frame fl=127 reads chunk 1047),
// xo @17408. Total 34816 B. No A in LDS.
#define SE 0
#define SO 17408

// 256 threads x 4 chunks + tail chunks 1024..1087 by wave 0 FULL-WAVE
// (partial-exec global_load_lds corrupts -- R12/R13 lesson).
#define STAGE_STREAM(src, bl) do {                                              \
  _Pragma("unroll") for (int p_ = 0; p_ < 4; ++p_) {                            \
    int q_ = p_ * 256 + tid;                                                    \
    GL2LDS((src) + (SWZ(q_) << 4), &lds[(bl) + q_ * 16]);                       \
  }                                                                             \
  if (tid < 64) {                                                               \
    int q_ = 1024 + tid;                                                        \
    GL2LDS((src) + (SWZ(q_) << 4), &lds[(bl) + q_ * 16]);                       \
  } } while (0)

// A fragment: one coalesced 1KB load per (mt,ks); addr = Ablk + kt*8192
// + wr*4096 + mt*2048 + ks*1024 + lane*16.
#define LOAD_A(dst, kt)                                                         \
  _Pragma("unroll") for (int mt_ = 0; mt_ < 2; ++mt_)                           \
  _Pragma("unroll") for (int ks_ = 0; ks_ < 2; ++ks_)                           \
    dst[mt_][ks_] = *(const i32x4*)(Ablk + (size_t)(kt) * 8192 +                \
                                    mt_ * 2048 + ks_ * 1024);

#define READ_B2(dst, ktm7, SB)                                                  \
  _Pragma("unroll") for (int nt_ = 0; nt_ < 2; ++nt_)                           \
  _Pragma("unroll") for (int ks_ = 0; ks_ < 2; ++ks_) {                         \
    int cp_ = (wc * 64 + nt_ * 32 + lr) * 8 + (ktm7) * 4 + 2 * ks_ + hi;        \
    dst[nt_][ks_] = *(const i32x4*)&lds[(SB) + (SWZ(cp_) << 4)];                \
  }

#define MFMA8(ACC, A_, B_) do {                                                 \
  __builtin_amdgcn_s_setprio(1);                                                \
  _Pragma("unroll") for (int ks_ = 0; ks_ < 2; ++ks_)                           \
  _Pragma("unroll") for (int mt_ = 0; mt_ < 2; ++mt_)                           \
  _Pragma("unroll") for (int nt_ = 0; nt_ < 2; ++nt_)                           \
    ACC[mt_][nt_] = __builtin_amdgcn_mfma_i32_32x32x32_i8(                      \
        A_[mt_][ks_], B_[nt_][ks_], ACC[mt_][nt_], 0, 0, 0);                    \
  __builtin_amdgcn_s_setprio(0);                                                \
  } while (0)

#define KT(kt, ACC, SB) do {                                                    \
    i32x4 af[2][2], bf[2][2];                                                   \
    LOAD_A(af, kt);                                                             \
    READ_B2(bf, (kt) & 7, SB);                                                  \
    MFMA8(ACC, af, bf);                                                         \
  } while (0)

__global__ __launch_bounds__(256, 2) void k_stft(const signed char* __restrict__ xe,
                                                 const signed char* __restrict__ xo,
                                                 const signed char* __restrict__ Afr,
                                                 const float2* __restrict__ tw,
                                                 float* __restrict__ out) {
  __shared__ __align__(16) signed char lds[34816];
  const int tid  = threadIdx.x;
  const int lane = tid & 63;
  const int wid  = tid >> 6;
  const int wr = wid >> 1;      // 0..1 (64 A-rows each)
  const int wc = wid & 1;       // 0..1 (64 frames each)
  const int lr = lane & 31;
  const int hi = lane >> 5;

  // XCD-bijective swizzle (R14): 1920 = 8*240; mblk fastest.
  const int bx = blockIdx.x;
  const int v = (bx & 7) * 240 + (bx >> 3);
  const int mblk = v & 3;
  const int nb = v >> 2;        // 0..479
  const int b  = nb / NBPB;
  const int f0 = (nb - b * NBPB) * BN;

  const signed char* se_src = xe + (size_t)b * SAMPH + (size_t)f0 * HOPH;
  const signed char* so_src = xo + (size_t)b * SAMPH + (size_t)f0 * HOPH;
  const signed char* Ablk = Afr + (size_t)mblk * 16 * 8192 +
                            wr * 4096 + lane * 16;

  i32x16 accE[2][2], accO[2][2];
  #pragma unroll
  for (int i = 0; i < 2; ++i)
    #pragma unroll
    for (int j = 0; j < 2; ++j)
      #pragma unroll
      for (int e = 0; e < 16; ++e) { accE[i][j][e] = 0; accO[i][j][e] = 0; }

  // prologue: both streams once; drain, publish. The ONLY barrier.
  STAGE_STREAM(se_src, SE);
  STAGE_STREAM(so_src, SO);
  WAIT0_BAR();

  // Free-running K-loop: no barriers, no vmcnt, no LDS writes. Compiler
  // pipelines A-loads (L2, coalesced 1KB/wave) under MFMA.
  #pragma unroll 2
  for (int kt = 0; kt < 8; ++kt)  KT(kt, accE, SE);
  #pragma unroll 2
  for (int kt = 8; kt < 16; ++kt) KT(kt, accO, SO);

  // ---- epilogue: in-register radix-2 combine, twiddle from table ----
  // C/D: col = lane&31, row = (reg&3)+8*(reg>>2)+4*hi.
  // fq = mblk*64 + wr*32 + mt*16 + aa*4 + 2*hi + q  (<= 255).
  const int fbase = mblk * 64 + wr * 32;
  #pragma unroll
  for (int nt = 0; nt < 2; ++nt) {
    const int col = wc * 64 + nt * 32 + lr;
    const int tfi = f0 + col;
    if (tfi >= NFRAMES) continue;
    float* op = out + (size_t)b * ((size_t)NFREQ * NFRAMES) + tfi;
    #pragma unroll
    for (int mt = 0; mt < 2; ++mt) {
      i32x16 vE = accE[mt][nt];
      i32x16 vO = accO[mt][nt];
      #pragma unroll
      for (int aa = 0; aa < 4; ++aa)
        #pragma unroll
        for (int q = 0; q < 2; ++q) {
          const int fq = fbase + mt * 16 + aa * 4 + 2 * hi + q;
          float Ere = (float)vE[aa * 4 + 2 * q];
          float Eim = (float)vE[aa * 4 + 2 * q + 1];
          float Ore = (float)vO[aa * 4 + 2 * q];
          float Oim = (float)vO[aa * 4 + 2 * q + 1];
          if (fq == 0) {
            float sp = Ere + Ore, sm = Ere - Ore;
            op[0]                     = DEQ2 * sp * sp;
            op[(size_t)512 * NFRAMES] = DEQ2 * sm * sm;
            op[(size_t)256 * NFRAMES] = DEQ2 * (Eim * Eim + Oim * Oim);
          } else {
            float2 t = tw[fq];
            float Pre = t.x * Ore + t.y * Oim;
            float Pim = t.x * Oim - t.y * Ore;
            float ar = Ere + Pre, ai = Eim + Pim;
            float br = Ere - Pre, bi = Eim - Pim;
            op[(size_t)fq * NFRAMES]         = DEQ2 * (ar * ar + ai * ai);
            op[(size_t)(512 - fq) * NFRAMES] = DEQ2 * (br * br + bi * bi);
          }
        }
    }
  }
}

extern "C" void kernel_launch(void* const* d_in, const int* in_sizes, int n_in,
                              void* d_out, int out_size, void* d_ws, size_t ws_size,
                              hipStream_t stream) {
  const float* x      = (const float*)d_in[0];
  const float* narr   = (const float*)d_in[1];
  const float* w      = (const float*)d_in[2];
  const float* window = (const float*)d_in[3];
  float* out = (float*)d_out;

  signed char* xe  = (signed char*)d_ws;
  signed char* xo  = xe + (size_t)BATCH * SAMPH;
  signed char* Afr = xo + (size_t)BATCH * SAMPH;
  float2*      tw  = (float2*)(Afr + AFR_BYTES);
  if (ws_size < XH_BYTES + AFR_BYTES + TW_BYTES) return;  // ~15.9 MB

  k_prep<<<PREP_BLOCKS, 256, 0, stream>>>(x, narr, w, window, xe, xo, Afr, tw);
  k_stft<<<NWG, 256, 0, stream>>>(xe, xo, Afr, tw, out);
}

// Round 18
// 64.871 us; speedup vs baseline: 1.4857x; 1.0667x over previous
//
#include <hip/hip_runtime.h>
#include <hip/hip_bf16.h>
#include <stdint.h>
#include <math.h>

// STFT power spectrogram via radix-2 decimated INT8 MFMA GEMM with a
// persistent LDS sample-stream. X(f) = E(f') + e^{-i pi f/512} O(f'),
// S = |X|^2. E/O = 512-pt windowed DFTs of even/odd samples.
// CHAMPION (R14, 64.2 us): 256-thread blocks (4 waves 2x2, wave-tile 64x64),
// read:MFMA ratio 1.0, 2 blocks/CU; 1088-chunk stream (frame fl=127 reads
// chunk 1047) with full-wave tail staging; SWZ stream swizzle; SLOTM A
// swizzle; twiddle table epilogue. Restored verbatim after R15-R17
// structural variants all regressed (mb-loop, global-A, truncated stream).

#define NFFT     1024
#define NFREQ    513
#define BATCH    32
#define SAMPLES  480000
#define SAMPH    240000                // per-batch half-stream samples
#define HOPH     128                   // hop in half-stream
#define NFRAMES  1872
#define BN       128                   // frames per block
#define NBPB     15                    // 15*128 >= 1872
#define MBLKS    4                     // 128 E-rows (+128 O) per block
#define KTILES   16                    // 8 E + 8 O, 64-wide
#define NWG      (BATCH * NBPB * MBLKS)   // 1920 = 8 * 240

#define XH_BYTES  ((size_t)BATCH * SAMPLES)              // xe+xo total
#define AWS_BYTES ((size_t)MBLKS * KTILES * 128 * 64)    // 524,288
#define TW_BYTES  (513 * 8)

#define XMAX   6.5f
#define SCALE_X (127.0f / XMAX)
#define DEQ    (XMAX / 16129.0f)
#define DEQ2   (DEQ * DEQ)

#define QX_BLOCKS 1875
#define BA_BLOCKS 2048
#define PREP_BLOCKS (QX_BLOCKS + BA_BLOCKS + 1)

typedef __attribute__((ext_vector_type(4)))  int i32x4;
typedef __attribute__((ext_vector_type(16))) int i32x16;

#define SLOTM(r) ((((r) >> 1) & 3) ^ (((r) >> 3) & 1))
// Stream chunk swizzle (involution: mask from bits>=3 only).
#define SWZ(q) ((q) ^ ((((q) >> 3) ^ ((q) >> 6)) & 7))

// ---------------- fused prep: quant+deinterleave | build_A | twiddle ------
__global__ __launch_bounds__(256) void k_prep(const float* __restrict__ x,
                                              const float* __restrict__ narr,
                                              const float* __restrict__ w,
                                              const float* __restrict__ window,
                                              signed char* __restrict__ xe,
                                              signed char* __restrict__ xo,
                                              signed char* __restrict__ Aws,
                                              float2* __restrict__ tw) {
  const int bid = blockIdx.x;
  const int tid = threadIdx.x;
  if (bid < QX_BLOCKS) {
    size_t i = (size_t)bid * 256 + tid;
    const float4* x4 = (const float4*)x;
    union { signed char c[16]; uint4 v; } pe, po;
    #pragma unroll
    for (int j = 0; j < 8; ++j) {
      float4 a = x4[i * 8 + j];
      float qe  = fminf(127.f, fmaxf(-127.f, a.x * SCALE_X));
      float qo  = fminf(127.f, fmaxf(-127.f, a.y * SCALE_X));
      float qe2 = fminf(127.f, fmaxf(-127.f, a.z * SCALE_X));
      float qo2 = fminf(127.f, fmaxf(-127.f, a.w * SCALE_X));
      pe.c[j * 2]     = (signed char)__float2int_rn(qe);
      po.c[j * 2]     = (signed char)__float2int_rn(qo);
      pe.c[j * 2 + 1] = (signed char)__float2int_rn(qe2);
      po.c[j * 2 + 1] = (signed char)__float2int_rn(qo2);
    }
    ((uint4*)xe)[i] = pe.v;
    ((uint4*)xo)[i] = po.v;
  } else if (bid < QX_BLOCKS + BA_BLOCKS) {
    // A i8 [mblk][kt][r 0..127][slot 0..3][16]; kt<8 E (win[2j]), kt>=8 O.
    uint32_t E = (uint32_t)(bid - QX_BLOCKS) * 256 + tid;
    uint32_t e    = E & 15;
    uint32_t s    = (E >> 4) & 3;
    uint32_t r    = (E >> 6) & 127;
    uint32_t kt   = (E >> 13) & 15;
    uint32_t mblk = E >> 17;
    uint32_t er = mblk * 128 + r;
    uint32_t j  = (kt & 7) * 64 + ((s ^ SLOTM(r)) << 4) + e;   // 0..511
    uint32_t odd = (kt >> 3) & 1;
    uint32_t widx = (er == 1) ? 512u : (er & ~1u);
    float ang = w[widx] * narr[j];
    float sn, cs;
    sincosf(ang, &sn, &cs);
    float base = ((er & 1) && (er != 1)) ? -sn : cs;
    float val = 127.f * window[2 * j + odd] * base;
    Aws[E] = (signed char)__float2int_rn(val);
  } else {
    for (int j = tid; j <= 512; j += 256) {
      float st, ct;
      sincosf((float)j * (float)(M_PI / 512.0), &st, &ct);
      tw[j] = make_float2(ct, st);
    }
  }
}

// ---------------- main GEMM ----------------
#define GL2LDS(g, l) __builtin_amdgcn_global_load_lds( \
    (const __attribute__((address_space(1))) uint32_t*)(g), \
    (__attribute__((address_space(3))) uint32_t*)(l), 16, 0, 0)

#define WAITV4_BAR() asm volatile("s_waitcnt vmcnt(4)\ns_barrier" ::: "memory")
#define WAIT0_BAR()  asm volatile("s_waitcnt vmcnt(0)\ns_barrier" ::: "memory")
#define LGKM0_BAR()  asm volatile("s_waitcnt lgkmcnt(0)\ns_barrier" ::: "memory")

// LDS: xe stream @0 (17408 B = 1088 chunks), xo @17408, A ring @34816
// (4 slots x 8192). Total 67584 -> 2 blocks/CU.
#define SE 0
#define SO 17408
#define AR 34816

// 256 threads: 4 full chunks each + tail by wave 0 (full-wave, R13 lesson:
// partial-exec global_load_lds corrupts).
#define STAGE_STREAM(src, bl) do {                                              \
  _Pragma("unroll") for (int p_ = 0; p_ < 4; ++p_) {                            \
    int q_ = p_ * 256 + tid;                                                    \
    GL2LDS((src) + (SWZ(q_) << 4), &lds[(bl) + q_ * 16]);                       \
  }                                                                             \
  if (tid < 64) {                                                               \
    int q_ = 1024 + tid;                                                        \
    GL2LDS((src) + (SWZ(q_) << 4), &lds[(bl) + q_ * 16]);                       \
  }                                                                             \
} while (0)

// A tile = 8 KB = 512 chunks -> 2 per thread (2 vmcnt items per STAGE_A).
#define STAGE_A(kt) do {                                                        \
  _Pragma("unroll") for (int j_ = 0; j_ < 2; ++j_) {                            \
    int ci_ = j_ * 256 + tid;                                                   \
    GL2LDS(Aws + (((size_t)mblk * KTILES + (kt)) * 512 + ci_) * 16,             \
           &lds[AR + ((kt) & 3) * 8192 + ci_ * 16]);                            \
  } } while (0)

#define READ_A2(dst, kt)                                                        \
  _Pragma("unroll") for (int mt_ = 0; mt_ < 2; ++mt_)                           \
  _Pragma("unroll") for (int ks_ = 0; ks_ < 2; ++ks_) {                         \
    int r_ = wr * 64 + mt_ * 32 + lr;                                           \
    int sl_ = (ks_ * 2 + hi) ^ SLOTM(r_);                                       \
    dst[mt_][ks_] = *(const i32x4*)&lds[AR + ((kt) & 3) * 8192 + (r_ * 4 + sl_) * 16]; \
  }

#define READ_B2(dst, ktm7, SB)                                                  \
  _Pragma("unroll") for (int nt_ = 0; nt_ < 2; ++nt_)                           \
  _Pragma("unroll") for (int ks_ = 0; ks_ < 2; ++ks_) {                         \
    int cp_ = (wc * 64 + nt_ * 32 + lr) * 8 + (ktm7) * 4 + 2 * ks_ + hi;        \
    dst[nt_][ks_] = *(const i32x4*)&lds[(SB) + (SWZ(cp_) << 4)];                \
  }

#define MFMA8(ACC, A_, B_) do {                                                 \
  __builtin_amdgcn_s_setprio(1);                                                \
  _Pragma("unroll") for (int ks_ = 0; ks_ < 2; ++ks_)                           \
  _Pragma("unroll") for (int mt_ = 0; mt_ < 2; ++mt_)                           \
  _Pragma("unroll") for (int nt_ = 0; nt_ < 2; ++nt_)                           \
    ACC[mt_][nt_] = __builtin_amdgcn_mfma_i32_32x32x32_i8(                      \
        A_[mt_][ks_], B_[nt_][ks_], ACC[mt_][nt_], 0, 0, 0);                    \
  __builtin_amdgcn_s_setprio(0);                                                \
  } while (0)

// Ledger (4 stage-items/iter): iter0/1 entry 0/4 out -> vmcnt(4) no-op,
// reads prologue-drained A0..3. Steady (i>=2): 8 out -> vmcnt(4) completes
// A(2i),A(2i+1). i==6: no stage -> 4 out at i==7 -> vmcnt(0). LGKM0_BAR
// is the WAR fence before ring-slot overwrite.
#define ITER(i, ACC, SB) do {                                                   \
    if ((i) == 7) WAIT0_BAR(); else WAITV4_BAR();                               \
    i32x4 a0[2][2], a1[2][2], b0[2][2], b1[2][2];                               \
    READ_A2(a0, 2 * (i));     READ_B2(b0, (2 * (i)) & 7, SB);                   \
    READ_A2(a1, 2 * (i) + 1); READ_B2(b1, (2 * (i) + 1) & 7, SB);               \
    MFMA8(ACC, a0, b0);                                                         \
    MFMA8(ACC, a1, b1);                                                         \
    LGKM0_BAR();                                                                \
    if ((i) < 6) { STAGE_A(2 * (i) + 4); STAGE_A(2 * (i) + 5); }                \
  } while (0)

__global__ __launch_bounds__(256, 2) void k_stft(const signed char* __restrict__ xe,
                                                 const signed char* __restrict__ xo,
                                                 const signed char* __restrict__ Aws,
                                                 const float2* __restrict__ tw,
                                                 float* __restrict__ out) {
  __shared__ __align__(16) signed char lds[67584];
  const int tid  = threadIdx.x;
  const int lane = tid & 63;
  const int wid  = tid >> 6;
  const int wr = wid >> 1;      // 0..1 (64 A-rows each)
  const int wc = wid & 1;       // 0..1 (64 frames each)
  const int lr = lane & 31;
  const int hi = lane >> 5;

  // XCD-bijective swizzle: 1920 = 8*240; mblk fastest (stream shared x4).
  const int bx = blockIdx.x;
  const int v = (bx & 7) * 240 + (bx >> 3);
  const int mblk = v & 3;
  const int nb = v >> 2;        // 0..479
  const int b  = nb / NBPB;
  const int f0 = (nb - b * NBPB) * BN;

  const signed char* se_src = xe + (size_t)b * SAMPH + (size_t)f0 * HOPH;
  const signed char* so_src = xo + (size_t)b * SAMPH + (size_t)f0 * HOPH;

  i32x16 accE[2][2], accO[2][2];
  #pragma unroll
  for (int i = 0; i < 2; ++i)
    #pragma unroll
    for (int j = 0; j < 2; ++j)
      #pragma unroll
      for (int e = 0; e < 16; ++e) { accE[i][j][e] = 0; accO[i][j][e] = 0; }

  STAGE_STREAM(se_src, SE);
  STAGE_STREAM(so_src, SO);
  STAGE_A(0); STAGE_A(1); STAGE_A(2); STAGE_A(3);
  WAIT0_BAR();

  ITER(0, accE, SE); ITER(1, accE, SE); ITER(2, accE, SE); ITER(3, accE, SE);
  ITER(4, accO, SO); ITER(5, accO, SO); ITER(6, accO, SO); ITER(7, accO, SO);

  // ---- epilogue: in-register radix-2 combine, twiddle from table ----
  // C/D: col = lane&31, row = (reg&3)+8*(reg>>2)+4*hi.
  // fq = mblk*64 + wr*32 + mt*16 + aa*4 + 2*hi + q  (<= 255).
  const int fbase = mblk * 64 + wr * 32;
  #pragma unroll
  for (int nt = 0; nt < 2; ++nt) {
    const int col = wc * 64 + nt * 32 + lr;
    const int tfi = f0 + col;
    if (tfi >= NFRAMES) continue;
    float* op = out + (size_t)b * ((size_t)NFREQ * NFRAMES) + tfi;
    #pragma unroll
    for (int mt = 0; mt < 2; ++mt) {
      i32x16 vE = accE[mt][nt];
      i32x16 vO = accO[mt][nt];
      #pragma unroll
      for (int aa = 0; aa < 4; ++aa)
        #pragma unroll
        for (int q = 0; q < 2; ++q) {
          const int fq = fbase + mt * 16 + aa * 4 + 2 * hi + q;
          float Ere = (float)vE[aa * 4 + 2 * q];
          float Eim = (float)vE[aa * 4 + 2 * q + 1];
          float Ore = (float)vO[aa * 4 + 2 * q];
          float Oim = (float)vO[aa * 4 + 2 * q + 1];
          if (fq == 0) {
            float sp = Ere + Ore, sm = Ere - Ore;
            op[0]                     = DEQ2 * sp * sp;
            op[(size_t)512 * NFRAMES] = DEQ2 * sm * sm;
            op[(size_t)256 * NFRAMES] = DEQ2 * (Eim * Eim + Oim * Oim);
          } else {
            float2 t = tw[fq];
            float Pre = t.x * Ore + t.y * Oim;
            float Pim = t.x * Oim - t.y * Ore;
            float ar = Ere + Pre, ai = Eim + Pim;
            float br = Ere - Pre, bi = Eim - Pim;
            op[(size_t)fq * NFRAMES]         = DEQ2 * (ar * ar + ai * ai);
            op[(size_t)(512 - fq) * NFRAMES] = DEQ2 * (br * br + bi * bi);
          }
        }
    }
  }
}

extern "C" void kernel_launch(void* const* d_in, const int* in_sizes, int n_in,
                              void* d_out, int out_size, void* d_ws, size_t ws_size,
                              hipStream_t stream) {
  const float* x      = (const float*)d_in[0];
  const float* narr   = (const float*)d_in[1];
  const float* w      = (const float*)d_in[2];
  const float* window = (const float*)d_in[3];
  float* out = (float*)d_out;

  signed char* xe  = (signed char*)d_ws;
  signed char* xo  = xe + (size_t)BATCH * SAMPH;
  signed char* Aws = xo + (size_t)BATCH * SAMPH;
  float2*      tw  = (float2*)(Aws + AWS_BYTES);
  if (ws_size < XH_BYTES + AWS_BYTES + TW_BYTES) return;  // ~15.9 MB

  k_prep<<<PREP_BLOCKS, 256, 0, stream>>>(x, narr, w, window, xe, xo, Aws, tw);
  k_stft<<<NWG, 256, 0, stream>>>(xe, xo, Aws, tw, out);
}